// Round 7
// baseline (783.788 us; speedup 1.0000x reference)
//
#include <hip/hip_runtime.h>
#include <math.h>

// Problem constants (b=1, c=64, t=128, f=128, expand=4, n=16, K=4, r=4)
#define LSEQ 128          // sequence length (both stages)
#define NROW 128          // rows per stage
#define POS (LSEQ*NROW)   // 16384 positions
#define CDIM 64
#define DDIM 256
#define NSTATE 16
#define RDIM 4
#define KCONV 4

static __forceinline__ __device__ float dot4(float4 a, float4 b) {
    return a.x*b.x + a.y*b.y + a.z*b.z + a.w*b.w;
}

// ---------------------------------------------------------------------------
// Stage-1 input prep: seq_in[(fi*128 + t)*64 + cc] = x[(cc*128 + t)*128 + fi]
__global__ __launch_bounds__(256) void k_prep1(const float* __restrict__ x,
                                               float* __restrict__ seq_in) {
    __shared__ float tile[64][65];
    int t   = blockIdx.x & 127;
    int fi0 = (blockIdx.x >> 7) << 6;  // 0 or 64
    int lane = threadIdx.x & 63;
    int r    = threadIdx.x >> 6;       // 0..3
    #pragma unroll
    for (int i = 0; i < 16; i++) {
        int cc = 4*i + r;
        tile[cc][lane] = x[cc*16384 + t*128 + fi0 + lane];
    }
    __syncthreads();
    #pragma unroll
    for (int i = 0; i < 16; i++) {
        int fl = 4*i + r;
        seq_in[(fi0 + fl)*8192 + t*64 + lane] = tile[lane][fl];
    }
}

// Final: out[cc*16384 + t*128 + fi] = s[(t*128+fi)*64 + cc]
__global__ __launch_bounds__(256) void k_final(const float* __restrict__ s,
                                               float* __restrict__ outp) {
    __shared__ float tile[64][65];
    int t   = blockIdx.x & 127;
    int fi0 = (blockIdx.x >> 7) << 6;
    int lane = threadIdx.x & 63;
    int r    = threadIdx.x >> 6;
    #pragma unroll
    for (int i = 0; i < 16; i++) {
        int fl = 4*i + r;
        tile[fl][lane] = s[(((t << 7) + fi0 + fl) << 6) + lane];
    }
    __syncthreads();
    #pragma unroll
    for (int i = 0; i < 16; i++) {
        int cc = 4*i + r;
        outp[cc*16384 + (t << 7) + fi0 + lane] = tile[lane][cc];
    }
}

// ---------------------------------------------------------------------------
// in_proj (rstd fused), both directions in one launch.
// grid = 2 * POS/16 blocks of 128 threads; 16 positions per block; thread j
// owns 4 output channels {j, j+128, j+256, j+384}: first two -> xc_pre
// channels j/j+128, last two -> z channels j/j+128.
__global__ __launch_bounds__(128) void k_inproj(const float* __restrict__ seq_in,
                                                const float* __restrict__ nw_s,
                                                const float* __restrict__ ipw_s,
                                                float* __restrict__ xc_pre,
                                                float* __restrict__ zbuf) {
    __shared__ float xn[16][64];
    int dir = blockIdx.x >> 10;              // 1024 blocks per dir
    int g0  = (blockIdx.x & 1023) << 4;
    size_t dirOff = (size_t)dir * POS * DDIM;
    const float* nw  = nw_s  + dir*CDIM;
    const float* ipw = ipw_s + (size_t)dir * 2*DDIM*CDIM;

    int wv   = threadIdx.x >> 6;   // wave 0..1
    int lane = threadIdx.x & 63;
    float nwv = nw[lane];
    #pragma unroll
    for (int pi = wv; pi < 16; pi += 2) {
        int p = g0 + pi;
        int row = p >> 7, tau = p & 127;
        int s = dir ? (127 - tau) : tau;
        int q = (row << 7) + s;
        float v = seq_in[(q << 6) + lane];
        float ss = v*v;
        #pragma unroll
        for (int off = 32; off; off >>= 1) ss += __shfl_xor(ss, off, 64);
        float rs = rsqrtf(ss*(1.0f/64.0f) + 1e-5f);
        xn[pi][lane] = v*rs*nwv;
    }
    __syncthreads();

    int j = threadIdx.x;   // 0..127
    const float4* w0p = (const float4*)(ipw + (j << 6));
    const float4* w1p = (const float4*)(ipw + ((j + 128) << 6));
    const float4* w2p = (const float4*)(ipw + ((j + 256) << 6));
    const float4* w3p = (const float4*)(ipw + ((j + 384) << 6));
    float acc0[16], acc1[16], acc2[16], acc3[16];
    #pragma unroll
    for (int i = 0; i < 16; i++) { acc0[i] = 0.f; acc1[i] = 0.f; acc2[i] = 0.f; acc3[i] = 0.f; }
    #pragma unroll 4
    for (int k4 = 0; k4 < 16; k4++) {
        float4 wa = w0p[k4], wb = w1p[k4], wc = w2p[k4], wd = w3p[k4];
        #pragma unroll
        for (int i = 0; i < 16; i++) {
            float4 xv = *((const float4*)&xn[i][k4 << 2]);
            acc0[i] += dot4(wa, xv);
            acc1[i] += dot4(wb, xv);
            acc2[i] += dot4(wc, xv);
            acc3[i] += dot4(wd, xv);
        }
    }
    #pragma unroll
    for (int i = 0; i < 16; i++) {
        size_t base = dirOff + (size_t)(g0 + i)*DDIM;
        xc_pre[base + j]       = acc0[i];
        xc_pre[base + j + 128] = acc1[i];
        zbuf  [base + j]       = acc2[i];
        zbuf  [base + j + 128] = acc3[i];
    }
}

// ---------------------------------------------------------------------------
// causal dwconv(K=4)+silu fused with x_proj (256->36). Writes xcb and
// dbl[pos][36] (r||B||C). dt_proj moved into the scan.
// grid = 2 * POS/16 blocks of 256 threads.
__global__ __launch_bounds__(256) void k_convxproj(const float* __restrict__ xc_pre,
                                                   const float* __restrict__ cw_s,
                                                   const float* __restrict__ cb_s,
                                                   const float* __restrict__ xpw_s,
                                                   float* __restrict__ xcb,
                                                   float* __restrict__ dblg) {
    __shared__ float lx[16][260];    // conv+silu output, padded stride
    int dir = blockIdx.x >> 10;      // POS/16 = 1024 blocks per dir
    int g0  = (blockIdx.x & 1023) << 4;
    int tau0 = g0 & 127;
    size_t dirOff = (size_t)dir * POS * DDIM;
    const float* cw  = cw_s  + dir*DDIM*KCONV;
    const float* cb  = cb_s  + dir*DDIM;
    const float* xpw = xpw_s + (size_t)dir*36*DDIM;
    int t = threadIdx.x;

    // conv + silu for this thread's channel (ch = t) at 16 positions
    float r[19];
    #pragma unroll
    for (int j = 0; j < 19; j++) {
        r[j] = (tau0 == 0 && j < 3) ? 0.f
             : xc_pre[dirOff + (size_t)(g0 - 3 + j)*DDIM + t];
    }
    float c0 = cw[t*4], c1 = cw[t*4+1], c2 = cw[t*4+2], c3 = cw[t*4+3];
    float cbv = cb[t];
    #pragma unroll
    for (int i = 0; i < 16; i++) {
        float a = cbv + c0*r[i] + c1*r[i+1] + c2*r[i+2] + c3*r[i+3];
        float sv = a / (1.f + __expf(-a));
        lx[i][t] = sv;
        xcb[dirOff + (size_t)(g0 + i)*DDIM + t] = sv;
    }
    __syncthreads();

    // x_proj: 16 pos x 36 outputs = 576; oid -> pos = oid&15, j = oid>>4
    // weights straight from global: 4 distinct rows per wave, 16-lane broadcast
    #pragma unroll
    for (int rep = 0; rep < 3; rep++) {
        int oid = rep*256 + t;
        if (oid < 576) {
            int pos = oid & 15;
            int j   = oid >> 4;
            const float4* xr = (const float4*)&lx[pos][0];
            const float4* wr = (const float4*)(xpw + (j << 8));
            float a0 = 0.f, a1 = 0.f, a2 = 0.f, a3 = 0.f;
            #pragma unroll 4
            for (int k4 = 0; k4 < 64; k4 += 4) {
                float4 xv0 = xr[k4],   wv0 = wr[k4];
                float4 xv1 = xr[k4+1], wv1 = wr[k4+1];
                float4 xv2 = xr[k4+2], wv2 = wr[k4+2];
                float4 xv3 = xr[k4+3], wv3 = wr[k4+3];
                a0 += dot4(wv0, xv0);
                a1 += dot4(wv1, xv1);
                a2 += dot4(wv2, xv2);
                a3 += dot4(wv3, xv3);
            }
            dblg[(size_t)dir*POS*36 + (size_t)(g0 + pos)*36 + j] =
                (a0 + a1) + (a2 + a3);
        }
    }
}

// ---------------------------------------------------------------------------
// selective scan; dt_proj+softplus computed in-kernel from dbl.
// Block = (dir,row); thread = channel, 16 n-states in registers. Fuses +D*xc
// and *silu(z). Writes y in UNREVERSED (q-indexed) layout.
__global__ __launch_bounds__(256) void k_scan(const float* __restrict__ xc,
                                              const float* __restrict__ dblg,
                                              const float* __restrict__ dtw_s,
                                              const float* __restrict__ dtb_s,
                                              const float* __restrict__ Alog_s,
                                              const float* __restrict__ Dp_s,
                                              const float* __restrict__ zbuf,
                                              float* __restrict__ y) {
    __shared__ float sdbl[128*36];  // r[4],B[16],C[16] per tau: 18.4 KiB
    int dir = blockIdx.x >> 7;      // 128 blocks per dir
    int row = blockIdx.x & 127;
    int ch  = threadIdx.x;
    size_t dirOff = (size_t)dir * POS * DDIM;
    const float* Alog = Alog_s + dir*DDIM*NSTATE;
    const float* Dp   = Dp_s   + dir*DDIM;
    const float* dtw  = dtw_s  + dir*DDIM*RDIM;
    const float* dtb  = dtb_s  + dir*DDIM;

    {   // stage this row's dbl (layout identical, linear float4 copy)
        const float4* src = (const float4*)(dblg + (size_t)dir*POS*36
                                            + (size_t)row*128*36);
        float4* dst = (float4*)sdbl;
        for (int i = threadIdx.x; i < 128*36/4; i += 256) dst[i] = src[i];
    }
    float a[16], h[16];
    #pragma unroll
    for (int i = 0; i < 16; i++) {
        a[i] = -__expf(Alog[ch*16 + i]);
        h[i] = 0.f;
    }
    float dv = Dp[ch];
    float tw0 = dtw[ch*4], tw1 = dtw[ch*4+1], tw2 = dtw[ch*4+2], tw3 = dtw[ch*4+3];
    float tb  = dtb[ch];
    __syncthreads();

    size_t off = dirOff + ((size_t)row*128)*DDIM + ch;   // tau=0 of this row
    const size_t ybase = off;                             // y indexed by s
    // depth-2 software pipeline on the xc/z streams
    float x0 = xc[off],        z0 = zbuf[off];
    float x1 = xc[off + DDIM], z1 = zbuf[off + DDIM];
    for (int tau = 0; tau < 128; tau++) {
        float x2 = 0.f, z2 = 0.f;
        if (tau + 2 < 128) {
            size_t offn = off + 2*DDIM;
            x2 = xc[offn]; z2 = zbuf[offn];
        }
        const float* db = &sdbl[tau*36];
        float adt = tb + db[0]*tw0 + db[1]*tw1 + db[2]*tw2 + db[3]*tw3;
        float dtv = (adt > 0.f) ? (adt + log1pf(__expf(-adt)))
                                : log1pf(__expf(adt));
        float dtx = dtv*x0;
        const float* B = db + 4;
        const float* C = db + 20;
        float ac0 = 0.f, ac1 = 0.f, ac2 = 0.f, ac3 = 0.f;
        #pragma unroll
        for (int i = 0; i < 16; i += 4) {
            float dA0 = __expf(dtv*a[i]);
            float dA1 = __expf(dtv*a[i+1]);
            float dA2 = __expf(dtv*a[i+2]);
            float dA3 = __expf(dtv*a[i+3]);
            h[i]   = h[i]*dA0   + dtx*B[i];
            h[i+1] = h[i+1]*dA1 + dtx*B[i+1];
            h[i+2] = h[i+2]*dA2 + dtx*B[i+2];
            h[i+3] = h[i+3]*dA3 + dtx*B[i+3];
            ac0 += h[i]*C[i];
            ac1 += h[i+1]*C[i+1];
            ac2 += h[i+2]*C[i+2];
            ac3 += h[i+3]*C[i+3];
        }
        float yv = (ac0 + ac1) + (ac2 + ac3) + dv*x0;
        yv *= z0 / (1.f + __expf(-z0));
        int s = dir ? (127 - tau) : tau;
        y[ybase + (size_t)s*DDIM] = yv;   // q-layout
        x0 = x1; z0 = z1; x1 = x2; z1 = z2; off += DDIM;
    }
}

// ---------------------------------------------------------------------------
// out_proj (256->64) for both dirs + bidir residual concat + stage linear
// (128->64) + residual. Optionally writes output transposed (stage-1 ->
// stage-2 layout). grid = POS/16 blocks of 256 threads.
// Thread mapping: cc = tid&31 -> channels {cc, cc+32}; sub = tid>>5 ->
// positions {2sub, 2sub+1}. Each x-fragment LDS read serves 2 weight rows.
__global__ __launch_bounds__(256) void k_outlin(const float* __restrict__ y,  // [2][POS][256], q-layout
                                                const float* __restrict__ opw_s,
                                                const float* __restrict__ seq_in,
                                                const float* __restrict__ lw,
                                                const float* __restrict__ lb,
                                                float* __restrict__ seq_out,
                                                int twrite) {
    __shared__ float ly0[16][256];
    __shared__ float ly1[16][256];
    __shared__ float si[16][64];
    __shared__ float cat[16][128];
    int g0 = blockIdx.x << 4;
    for (int i = threadIdx.x; i < 16*256; i += 256) {
        ly0[i >> 8][i & 255] = y[((size_t)g0 << 8) + i];
        ly1[i >> 8][i & 255] = y[(size_t)POS*DDIM + ((size_t)g0 << 8) + i];
    }
    for (int i = threadIdx.x; i < 16*64; i += 256)
        si[i >> 6][i & 63] = seq_in[((size_t)g0 << 6) + i];
    __syncthreads();

    int cc  = threadIdx.x & 31;        // this thread: cc and cc+32
    int sub = threadIdx.x >> 5;        // 0..7
    int i0 = sub << 1, i1 = i0 + 1;
    const float4* wf0 = (const float4*)(opw_s + (cc << 8));
    const float4* wf1 = (const float4*)(opw_s + ((cc + 32) << 8));
    const float4* wb0 = (const float4*)(opw_s + CDIM*DDIM + (cc << 8));
    const float4* wb1 = (const float4*)(opw_s + CDIM*DDIM + ((cc + 32) << 8));
    float f00 = 0.f, f01 = 0.f, f10 = 0.f, f11 = 0.f;
    float b00 = 0.f, b01 = 0.f, b10 = 0.f, b11 = 0.f;
    for (int k4 = 0; k4 < 64; k4++) {
        float4 xf0 = *((const float4*)&ly0[i0][k4 << 2]);
        float4 xf1 = *((const float4*)&ly0[i1][k4 << 2]);
        float4 xb0 = *((const float4*)&ly1[i0][k4 << 2]);
        float4 xb1 = *((const float4*)&ly1[i1][k4 << 2]);
        float4 wa = wf0[k4], wb = wf1[k4], wc = wb0[k4], wd = wb1[k4];
        f00 += dot4(wa, xf0);  f10 += dot4(wa, xf1);
        f01 += dot4(wb, xf0);  f11 += dot4(wb, xf1);
        b00 += dot4(wc, xb0);  b10 += dot4(wc, xb1);
        b01 += dot4(wd, xb0);  b11 += dot4(wd, xb1);
    }
    cat[i0][cc]           = si[i0][cc]      + f00;
    cat[i1][cc]           = si[i1][cc]      + f10;
    cat[i0][cc + 32]      = si[i0][cc + 32] + f01;
    cat[i1][cc + 32]      = si[i1][cc + 32] + f11;
    cat[i0][64 + cc]      = si[i0][cc]      + b00;
    cat[i1][64 + cc]      = si[i1][cc]      + b10;
    cat[i0][64 + cc + 32] = si[i0][cc + 32] + b01;
    cat[i1][64 + cc + 32] = si[i1][cc + 32] + b11;
    __syncthreads();

    // stage linear: 128 -> 64, cat float4 reads, lw coalesced scalar reads
    float a00 = lb[cc], a01 = lb[cc + 32];
    float a10 = a00,    a11 = a01;
    for (int k4 = 0; k4 < 32; k4++) {
        int k = k4 << 2;
        float4 cA = *((const float4*)&cat[i0][k]);
        float4 cB = *((const float4*)&cat[i1][k]);
        const float* lr = lw + (size_t)k*64;
        float wA0 = lr[cc],       wA1 = lr[cc + 32];
        float wB0 = lr[64 + cc],  wB1 = lr[64 + cc + 32];
        float wC0 = lr[128 + cc], wC1 = lr[128 + cc + 32];
        float wD0 = lr[192 + cc], wD1 = lr[192 + cc + 32];
        a00 += cA.x*wA0 + cA.y*wB0 + cA.z*wC0 + cA.w*wD0;
        a01 += cA.x*wA1 + cA.y*wB1 + cA.z*wC1 + cA.w*wD1;
        a10 += cB.x*wA0 + cB.y*wB0 + cB.z*wC0 + cB.w*wD0;
        a11 += cB.x*wA1 + cB.y*wB1 + cB.z*wC1 + cB.w*wD1;
    }
    #pragma unroll
    for (int v = 0; v < 4; v++) {
        int i  = (v & 1) ? i1 : i0;
        int c  = (v & 2) ? (cc + 32) : cc;
        float val = ((v == 0) ? a00 : (v == 1) ? a10 : (v == 2) ? a01 : a11)
                    + si[i][c];
        int p = g0 + i;
        if (twrite) {
            int dstp = ((p & 127) << 7) + (p >> 7);
            seq_out[((size_t)dstp << 6) + c] = val;
        } else {
            seq_out[((size_t)p << 6) + c] = val;
        }
    }
}

// ---------------------------------------------------------------------------
extern "C" void kernel_launch(void* const* d_in, const int* in_sizes, int n_in,
                              void* d_out, int out_size, void* d_ws, size_t ws_size,
                              hipStream_t stream) {
    (void)in_sizes; (void)n_in; (void)out_size; (void)ws_size;
    const float* x      = (const float*)d_in[0];
    const float* norm_w = (const float*)d_in[1];
    const float* ipw    = (const float*)d_in[2];
    const float* cw     = (const float*)d_in[3];
    const float* cb     = (const float*)d_in[4];
    const float* xpw    = (const float*)d_in[5];
    const float* dtw    = (const float*)d_in[6];
    const float* dtbp   = (const float*)d_in[7];
    const float* Alog   = (const float*)d_in[8];
    const float* Dp     = (const float*)d_in[9];
    const float* opw    = (const float*)d_in[10];
    const float* tlw    = (const float*)d_in[11];
    const float* tlb    = (const float*)d_in[12];
    const float* flw    = (const float*)d_in[13];
    const float* flb    = (const float*)d_in[14];
    float* outp = (float*)d_out;

    float* ws       = (float*)d_ws;
    float* seq_in   = ws;                            // POS*64
    float* xc_pre   = seq_in  + (size_t)POS*64;      // 2*POS*256 (reused as y)
    float* zbuf     = xc_pre  + (size_t)2*POS*256;   // 2*POS*256
    float* xcb      = zbuf    + (size_t)2*POS*256;   // 2*POS*256
    float* dblbuf   = xcb     + (size_t)2*POS*256;   // 2*POS*36
    float* seq_out  = dblbuf  + (size_t)2*POS*36;    // POS*64

    auto stage = [&](int st, const float* lw, const float* lb, int twrite,
                     float* sout) {
        int pi = 2*st;
        k_inproj   <<<2*POS/16, 128, 0, stream>>>(seq_in,
                        norm_w + pi*CDIM, ipw + (size_t)pi*2*DDIM*CDIM,
                        xc_pre, zbuf);
        k_convxproj<<<2*POS/16, 256, 0, stream>>>(xc_pre,
                        cw + pi*DDIM*KCONV, cb + pi*DDIM,
                        xpw + (size_t)pi*36*DDIM,
                        xcb, dblbuf);
        k_scan     <<<2*NROW, 256, 0, stream>>>(xcb, dblbuf,
                        dtw + pi*DDIM*RDIM, dtbp + pi*DDIM,
                        Alog + (size_t)pi*DDIM*NSTATE, Dp + pi*DDIM,
                        zbuf, xc_pre);   // y written into xc_pre (q-layout)
        k_outlin   <<<POS/16, 256, 0, stream>>>(xc_pre,
                        opw + (size_t)pi*CDIM*DDIM, seq_in, lw, lb,
                        sout, twrite);
    };

    // stage 1 (time mamba), output written directly in stage-2 layout
    k_prep1<<<256, 256, 0, stream>>>(x, seq_in);
    stage(0, tlw, tlb, 1, seq_out);

    // stage 2 (freq mamba)
    {
        float* tmp = seq_in; seq_in = seq_out; seq_out = tmp;
    }
    stage(1, flw, flb, 0, seq_out);

    // write back
    k_final<<<256, 256, 0, stream>>>(seq_out, outp);
}

// Round 8
// 677.402 us; speedup vs baseline: 1.1571x; 1.1571x over previous
//
#include <hip/hip_runtime.h>
#include <math.h>

// Problem constants (b=1, c=64, t=128, f=128, expand=4, n=16, K=4, r=4)
#define LSEQ 128          // sequence length (both stages)
#define NROW 128          // rows per stage
#define POS (LSEQ*NROW)   // 16384 positions
#define CDIM 64
#define DDIM 256
#define NSTATE 16
#define RDIM 4
#define KCONV 4

static __forceinline__ __device__ float dot4(float4 a, float4 b) {
    return a.x*b.x + a.y*b.y + a.z*b.z + a.w*b.w;
}

// ---------------------------------------------------------------------------
// Stage-1 input prep: seq_in[(fi*128 + t)*64 + cc] = x[(cc*128 + t)*128 + fi]
__global__ __launch_bounds__(256) void k_prep1(const float* __restrict__ x,
                                               float* __restrict__ seq_in) {
    __shared__ float tile[64][65];
    int t   = blockIdx.x & 127;
    int fi0 = (blockIdx.x >> 7) << 6;  // 0 or 64
    int lane = threadIdx.x & 63;
    int r    = threadIdx.x >> 6;       // 0..3
    #pragma unroll
    for (int i = 0; i < 16; i++) {
        int cc = 4*i + r;
        tile[cc][lane] = x[cc*16384 + t*128 + fi0 + lane];
    }
    __syncthreads();
    #pragma unroll
    for (int i = 0; i < 16; i++) {
        int fl = 4*i + r;
        seq_in[(fi0 + fl)*8192 + t*64 + lane] = tile[lane][fl];
    }
}

// Final: out[cc*16384 + t*128 + fi] = s[(t*128+fi)*64 + cc]
__global__ __launch_bounds__(256) void k_final(const float* __restrict__ s,
                                               float* __restrict__ outp) {
    __shared__ float tile[64][65];
    int t   = blockIdx.x & 127;
    int fi0 = (blockIdx.x >> 7) << 6;
    int lane = threadIdx.x & 63;
    int r    = threadIdx.x >> 6;
    #pragma unroll
    for (int i = 0; i < 16; i++) {
        int fl = 4*i + r;
        tile[fl][lane] = s[(((t << 7) + fi0 + fl) << 6) + lane];
    }
    __syncthreads();
    #pragma unroll
    for (int i = 0; i < 16; i++) {
        int cc = 4*i + r;
        outp[cc*16384 + (t << 7) + fi0 + lane] = tile[lane][cc];
    }
}

// ---------------------------------------------------------------------------
// in_proj (rstd fused), both directions in one launch.
// grid = 2 * POS/16 blocks of 128 threads; 16 positions per block; thread j
// owns 4 output channels {j, j+128, j+256, j+384}: first two -> xc_pre
// channels j/j+128, last two -> z channels j/j+128.
__global__ __launch_bounds__(128) void k_inproj(const float* __restrict__ seq_in,
                                                const float* __restrict__ nw_s,
                                                const float* __restrict__ ipw_s,
                                                float* __restrict__ xc_pre,
                                                float* __restrict__ zbuf) {
    __shared__ float xn[16][64];
    int dir = blockIdx.x >> 10;              // 1024 blocks per dir
    int g0  = (blockIdx.x & 1023) << 4;
    size_t dirOff = (size_t)dir * POS * DDIM;
    const float* nw  = nw_s  + dir*CDIM;
    const float* ipw = ipw_s + (size_t)dir * 2*DDIM*CDIM;

    int wv   = threadIdx.x >> 6;   // wave 0..1
    int lane = threadIdx.x & 63;
    float nwv = nw[lane];
    #pragma unroll
    for (int pi = wv; pi < 16; pi += 2) {
        int p = g0 + pi;
        int row = p >> 7, tau = p & 127;
        int s = dir ? (127 - tau) : tau;
        int q = (row << 7) + s;
        float v = seq_in[(q << 6) + lane];
        float ss = v*v;
        #pragma unroll
        for (int off = 32; off; off >>= 1) ss += __shfl_xor(ss, off, 64);
        float rs = rsqrtf(ss*(1.0f/64.0f) + 1e-5f);
        xn[pi][lane] = v*rs*nwv;
    }
    __syncthreads();

    int j = threadIdx.x;   // 0..127
    const float4* w0p = (const float4*)(ipw + (j << 6));
    const float4* w1p = (const float4*)(ipw + ((j + 128) << 6));
    const float4* w2p = (const float4*)(ipw + ((j + 256) << 6));
    const float4* w3p = (const float4*)(ipw + ((j + 384) << 6));
    float acc0[16], acc1[16], acc2[16], acc3[16];
    #pragma unroll
    for (int i = 0; i < 16; i++) { acc0[i] = 0.f; acc1[i] = 0.f; acc2[i] = 0.f; acc3[i] = 0.f; }
    #pragma unroll 4
    for (int k4 = 0; k4 < 16; k4++) {
        float4 wa = w0p[k4], wb = w1p[k4], wc = w2p[k4], wd = w3p[k4];
        #pragma unroll
        for (int i = 0; i < 16; i++) {
            float4 xv = *((const float4*)&xn[i][k4 << 2]);
            acc0[i] += dot4(wa, xv);
            acc1[i] += dot4(wb, xv);
            acc2[i] += dot4(wc, xv);
            acc3[i] += dot4(wd, xv);
        }
    }
    #pragma unroll
    for (int i = 0; i < 16; i++) {
        size_t base = dirOff + (size_t)(g0 + i)*DDIM;
        xc_pre[base + j]       = acc0[i];
        xc_pre[base + j + 128] = acc1[i];
        zbuf  [base + j]       = acc2[i];
        zbuf  [base + j + 128] = acc3[i];
    }
}

// ---------------------------------------------------------------------------
// causal dwconv(K=4)+silu fused with x_proj (256->36). Writes xcb and
// dbl[pos][36] (r||B||C). dt_proj moved into the scan.
// grid = 2 * POS/16 blocks of 256 threads.
__global__ __launch_bounds__(256) void k_convxproj(const float* __restrict__ xc_pre,
                                                   const float* __restrict__ cw_s,
                                                   const float* __restrict__ cb_s,
                                                   const float* __restrict__ xpw_s,
                                                   float* __restrict__ xcb,
                                                   float* __restrict__ dblg) {
    __shared__ float lx[16][260];    // conv+silu output, padded stride
    int dir = blockIdx.x >> 10;      // POS/16 = 1024 blocks per dir
    int g0  = (blockIdx.x & 1023) << 4;
    int tau0 = g0 & 127;
    size_t dirOff = (size_t)dir * POS * DDIM;
    const float* cw  = cw_s  + dir*DDIM*KCONV;
    const float* cb  = cb_s  + dir*DDIM;
    const float* xpw = xpw_s + (size_t)dir*36*DDIM;
    int t = threadIdx.x;

    // conv + silu for this thread's channel (ch = t) at 16 positions
    float r[19];
    #pragma unroll
    for (int j = 0; j < 19; j++) {
        r[j] = (tau0 == 0 && j < 3) ? 0.f
             : xc_pre[dirOff + (size_t)(g0 - 3 + j)*DDIM + t];
    }
    float c0 = cw[t*4], c1 = cw[t*4+1], c2 = cw[t*4+2], c3 = cw[t*4+3];
    float cbv = cb[t];
    #pragma unroll
    for (int i = 0; i < 16; i++) {
        float a = cbv + c0*r[i] + c1*r[i+1] + c2*r[i+2] + c3*r[i+3];
        float sv = a / (1.f + __expf(-a));
        lx[i][t] = sv;
        xcb[dirOff + (size_t)(g0 + i)*DDIM + t] = sv;
    }
    __syncthreads();

    // x_proj: 16 pos x 36 outputs = 576; oid -> pos = oid&15, j = oid>>4
    // weights straight from global: 4 distinct rows per wave, 16-lane broadcast
    #pragma unroll
    for (int rep = 0; rep < 3; rep++) {
        int oid = rep*256 + t;
        if (oid < 576) {
            int pos = oid & 15;
            int j   = oid >> 4;
            const float4* xr = (const float4*)&lx[pos][0];
            const float4* wr = (const float4*)(xpw + (j << 8));
            float a0 = 0.f, a1 = 0.f, a2 = 0.f, a3 = 0.f;
            #pragma unroll 4
            for (int k4 = 0; k4 < 64; k4 += 4) {
                float4 xv0 = xr[k4],   wv0 = wr[k4];
                float4 xv1 = xr[k4+1], wv1 = wr[k4+1];
                float4 xv2 = xr[k4+2], wv2 = wr[k4+2];
                float4 xv3 = xr[k4+3], wv3 = wr[k4+3];
                a0 += dot4(wv0, xv0);
                a1 += dot4(wv1, xv1);
                a2 += dot4(wv2, xv2);
                a3 += dot4(wv3, xv3);
            }
            dblg[(size_t)dir*POS*36 + (size_t)(g0 + pos)*36 + j] =
                (a0 + a1) + (a2 + a3);
        }
    }
}

// ---------------------------------------------------------------------------
// selective scan; dt_proj+softplus computed in-kernel from dbl.
// Block = (dir,row), 512 threads: thread = (ch, half) with 8 n-states each,
// __shfl_xor(1) combine. Fuses +D*xc and *silu(z). Writes y in UNREVERSED
// (q-indexed) layout.
__global__ __launch_bounds__(512) void k_scan(const float* __restrict__ xc,
                                              const float* __restrict__ dblg,
                                              const float* __restrict__ dtw_s,
                                              const float* __restrict__ dtb_s,
                                              const float* __restrict__ Alog_s,
                                              const float* __restrict__ Dp_s,
                                              const float* __restrict__ zbuf,
                                              float* __restrict__ y) {
    __shared__ float sdbl[128*36];  // r[4],B[16],C[16] per tau: 18.4 KiB
    int dir  = blockIdx.x >> 7;     // 128 blocks per dir
    int row  = blockIdx.x & 127;
    int ch   = threadIdx.x >> 1;
    int half = threadIdx.x & 1;
    int s0   = half << 3;           // state offset 0 or 8
    size_t dirOff = (size_t)dir * POS * DDIM;
    const float* Alog = Alog_s + dir*DDIM*NSTATE;
    const float* Dp   = Dp_s   + dir*DDIM;
    const float* dtw  = dtw_s  + dir*DDIM*RDIM;
    const float* dtb  = dtb_s  + dir*DDIM;

    {   // stage this row's dbl (layout identical, linear float4 copy)
        const float4* src = (const float4*)(dblg + (size_t)dir*POS*36
                                            + (size_t)row*128*36);
        float4* dst = (float4*)sdbl;
        for (int i = threadIdx.x; i < 128*36/4; i += 512) dst[i] = src[i];
    }
    float a[8], h[8];
    #pragma unroll
    for (int j = 0; j < 8; j++) {
        a[j] = -__expf(Alog[ch*16 + s0 + j]);
        h[j] = 0.f;
    }
    float dv = Dp[ch];
    float tw0 = dtw[ch*4], tw1 = dtw[ch*4+1], tw2 = dtw[ch*4+2], tw3 = dtw[ch*4+3];
    float tb  = dtb[ch];
    __syncthreads();

    size_t off = dirOff + ((size_t)row*128)*DDIM + ch;   // tau=0 of this row
    const size_t ybase = off;                             // y indexed by s
    // depth-2 software pipeline on the xc/z streams
    float x0 = xc[off],        z0 = zbuf[off];
    float x1 = xc[off + DDIM], z1 = zbuf[off + DDIM];
    for (int tau = 0; tau < 128; tau++) {
        float x2 = 0.f, z2 = 0.f;
        if (tau + 2 < 128) {
            size_t offn = off + 2*DDIM;
            x2 = xc[offn]; z2 = zbuf[offn];
        }
        const float* db = &sdbl[tau*36];
        float adt = tb + db[0]*tw0 + db[1]*tw1 + db[2]*tw2 + db[3]*tw3;
        float dtv = (adt > 0.f) ? (adt + log1pf(__expf(-adt)))
                                : log1pf(__expf(adt));
        float dtx = dtv*x0;
        const float* B = db + 4 + s0;
        const float* C = db + 20 + s0;
        float ac0 = 0.f, ac1 = 0.f, ac2 = 0.f, ac3 = 0.f;
        #pragma unroll
        for (int j = 0; j < 8; j += 4) {
            float dA0 = __expf(dtv*a[j]);
            float dA1 = __expf(dtv*a[j+1]);
            float dA2 = __expf(dtv*a[j+2]);
            float dA3 = __expf(dtv*a[j+3]);
            h[j]   = h[j]*dA0   + dtx*B[j];
            h[j+1] = h[j+1]*dA1 + dtx*B[j+1];
            h[j+2] = h[j+2]*dA2 + dtx*B[j+2];
            h[j+3] = h[j+3]*dA3 + dtx*B[j+3];
            ac0 += h[j]*C[j];
            ac1 += h[j+1]*C[j+1];
            ac2 += h[j+2]*C[j+2];
            ac3 += h[j+3]*C[j+3];
        }
        float acc = (ac0 + ac1) + (ac2 + ac3);
        acc += __shfl_xor(acc, 1, 64);       // combine the two state-halves
        if (!half) {
            float yv = acc + dv*x0;
            yv *= z0 / (1.f + __expf(-z0));
            int s = dir ? (127 - tau) : tau;
            y[ybase + (size_t)s*DDIM] = yv;  // q-layout
        }
        x0 = x1; z0 = z1; x1 = x2; z1 = z2; off += DDIM;
    }
}

// ---------------------------------------------------------------------------
// out_proj (256->64) both dirs + bidir residual concat + stage linear
// (128->64) + residual. grid = POS/32 blocks (512) of 256 threads.
// Phase 1: quarter q=tid>>6 -> (dir=q&1, posgroup=q>>1), cc=tid&63.
//   Each thread streams ONE 1KB weight row once, amortized over 16 positions
//   (acc[16]); y reads are wave-uniform (broadcast transactions).
// Phase 2: tid -> (cc=tid&63, grp=tid>>6), 8 positions each; lw coalesced,
//   cat broadcast from LDS.
__global__ __launch_bounds__(256) void k_outlin(const float* __restrict__ y,  // [2][POS][256], q-layout
                                                const float* __restrict__ opw_s,
                                                const float* __restrict__ seq_in,
                                                const float* __restrict__ lw,
                                                const float* __restrict__ lb,
                                                float* __restrict__ seq_out,
                                                int twrite) {
    __shared__ float cat[32][128];   // 16 KiB
    int tid = threadIdx.x;
    int g0  = blockIdx.x << 5;       // 32 positions per block

    // ---- phase 1: out_proj ----
    {
        int cc  = tid & 63;
        int q   = tid >> 6;          // 0..3
        int dir = q & 1;
        int pg  = q >> 1;            // position half: 0 or 1
        int p0  = g0 + (pg << 4);
        const float* yb = y + (size_t)dir*POS*DDIM + (size_t)p0*DDIM;
        const float4* wp = (const float4*)(opw_s + (size_t)dir*CDIM*DDIM
                                           + (size_t)cc*DDIM);
        float acc[16];
        #pragma unroll
        for (int i = 0; i < 16; i++) acc[i] = 0.f;
        for (int k4 = 0; k4 < 64; k4++) {
            float4 w = wp[k4];
            #pragma unroll
            for (int i = 0; i < 16; i++) {
                float4 xv = *((const float4*)(yb + (size_t)i*DDIM + (k4 << 2)));
                acc[i] += dot4(w, xv);
            }
        }
        #pragma unroll
        for (int i = 0; i < 16; i++) {
            float siv = seq_in[(size_t)(p0 + i)*CDIM + cc];
            cat[(pg << 4) + i][(dir << 6) + cc] = siv + acc[i];
        }
    }
    __syncthreads();

    // ---- phase 2: stage linear (128 -> 64) + residual ----
    {
        int cc  = tid & 63;
        int grp = tid >> 6;          // 0..3
        int ib  = grp << 3;          // 8 positions per thread
        float bv = lb[cc];
        float acc2[8];
        #pragma unroll
        for (int ii = 0; ii < 8; ii++) acc2[ii] = bv;
        for (int k4 = 0; k4 < 32; k4++) {
            int k = k4 << 2;
            float w0 = lw[(k + 0)*64 + cc];
            float w1 = lw[(k + 1)*64 + cc];
            float w2 = lw[(k + 2)*64 + cc];
            float w3 = lw[(k + 3)*64 + cc];
            #pragma unroll
            for (int ii = 0; ii < 8; ii++) {
                float4 cv = *((const float4*)&cat[ib + ii][k]);
                acc2[ii] += cv.x*w0 + cv.y*w1 + cv.z*w2 + cv.w*w3;
            }
        }
        #pragma unroll
        for (int ii = 0; ii < 8; ii++) {
            int p = g0 + ib + ii;
            float val = acc2[ii] + seq_in[(size_t)p*CDIM + cc];
            if (twrite) {
                // stage-1 -> stage-2 layout: dst position (t*128+fi), p = fi*128+t
                int dstp = ((p & 127) << 7) + (p >> 7);
                seq_out[((size_t)dstp << 6) + cc] = val;
            } else {
                seq_out[((size_t)p << 6) + cc] = val;
            }
        }
    }
}

// ---------------------------------------------------------------------------
extern "C" void kernel_launch(void* const* d_in, const int* in_sizes, int n_in,
                              void* d_out, int out_size, void* d_ws, size_t ws_size,
                              hipStream_t stream) {
    (void)in_sizes; (void)n_in; (void)out_size; (void)ws_size;
    const float* x      = (const float*)d_in[0];
    const float* norm_w = (const float*)d_in[1];
    const float* ipw    = (const float*)d_in[2];
    const float* cw     = (const float*)d_in[3];
    const float* cb     = (const float*)d_in[4];
    const float* xpw    = (const float*)d_in[5];
    const float* dtw    = (const float*)d_in[6];
    const float* dtbp   = (const float*)d_in[7];
    const float* Alog   = (const float*)d_in[8];
    const float* Dp     = (const float*)d_in[9];
    const float* opw    = (const float*)d_in[10];
    const float* tlw    = (const float*)d_in[11];
    const float* tlb    = (const float*)d_in[12];
    const float* flw    = (const float*)d_in[13];
    const float* flb    = (const float*)d_in[14];
    float* outp = (float*)d_out;

    float* ws       = (float*)d_ws;
    float* seq_in   = ws;                            // POS*64
    float* xc_pre   = seq_in  + (size_t)POS*64;      // 2*POS*256 (reused as y)
    float* zbuf     = xc_pre  + (size_t)2*POS*256;   // 2*POS*256
    float* xcb      = zbuf    + (size_t)2*POS*256;   // 2*POS*256
    float* dblbuf   = xcb     + (size_t)2*POS*256;   // 2*POS*36
    float* seq_out  = dblbuf  + (size_t)2*POS*36;    // POS*64

    auto stage = [&](int st, const float* lw, const float* lb, int twrite,
                     float* sout) {
        int pi = 2*st;
        k_inproj   <<<2*POS/16, 128, 0, stream>>>(seq_in,
                        norm_w + pi*CDIM, ipw + (size_t)pi*2*DDIM*CDIM,
                        xc_pre, zbuf);
        k_convxproj<<<2*POS/16, 256, 0, stream>>>(xc_pre,
                        cw + pi*DDIM*KCONV, cb + pi*DDIM,
                        xpw + (size_t)pi*36*DDIM,
                        xcb, dblbuf);
        k_scan     <<<2*NROW, 512, 0, stream>>>(xcb, dblbuf,
                        dtw + pi*DDIM*RDIM, dtbp + pi*DDIM,
                        Alog + (size_t)pi*DDIM*NSTATE, Dp + pi*DDIM,
                        zbuf, xc_pre);   // y written into xc_pre (q-layout)
        k_outlin   <<<POS/32, 256, 0, stream>>>(xc_pre,
                        opw + (size_t)pi*CDIM*DDIM, seq_in, lw, lb,
                        sout, twrite);
    };

    // stage 1 (time mamba), output written directly in stage-2 layout
    k_prep1<<<256, 256, 0, stream>>>(x, seq_in);
    stage(0, tlw, tlb, 1, seq_out);

    // stage 2 (freq mamba)
    {
        float* tmp = seq_in; seq_in = seq_out; seq_out = tmp;
    }
    stage(1, flw, flb, 0, seq_out);

    // write back
    k_final<<<256, 256, 0, stream>>>(seq_out, outp);
}

// Round 11
// 634.092 us; speedup vs baseline: 1.2361x; 1.0683x over previous
//
#include <hip/hip_runtime.h>
#include <math.h>

// Problem constants (b=1, c=64, t=128, f=128, expand=4, n=16, K=4, r=4)
#define LSEQ 128          // sequence length (both stages)
#define NROW 128          // rows per stage
#define POS (LSEQ*NROW)   // 16384 positions
#define CDIM 64
#define DDIM 256
#define NSTATE 16
#define RDIM 4
#define KCONV 4

static __forceinline__ __device__ float dot4(float4 a, float4 b) {
    return a.x*b.x + a.y*b.y + a.z*b.z + a.w*b.w;
}
static __forceinline__ __device__ float fast_silu(float v) {
    return v * __builtin_amdgcn_rcpf(1.f + __expf(-v));
}

// ---------------------------------------------------------------------------
// Stage-1 input prep: seq_in[(fi*128 + t)*64 + cc] = x[(cc*128 + t)*128 + fi]
__global__ __launch_bounds__(256) void k_prep1(const float* __restrict__ x,
                                               float* __restrict__ seq_in) {
    __shared__ float tile[64][65];
    int t   = blockIdx.x & 127;
    int fi0 = (blockIdx.x >> 7) << 6;  // 0 or 64
    int lane = threadIdx.x & 63;
    int r    = threadIdx.x >> 6;       // 0..3
    #pragma unroll
    for (int i = 0; i < 16; i++) {
        int cc = 4*i + r;
        tile[cc][lane] = x[cc*16384 + t*128 + fi0 + lane];
    }
    __syncthreads();
    #pragma unroll
    for (int i = 0; i < 16; i++) {
        int fl = 4*i + r;
        seq_in[(fi0 + fl)*8192 + t*64 + lane] = tile[lane][fl];
    }
}

// Final: out[cc*16384 + t*128 + fi] = s[(t*128+fi)*64 + cc]
__global__ __launch_bounds__(256) void k_final(const float* __restrict__ s,
                                               float* __restrict__ outp) {
    __shared__ float tile[64][65];
    int t   = blockIdx.x & 127;
    int fi0 = (blockIdx.x >> 7) << 6;
    int lane = threadIdx.x & 63;
    int r    = threadIdx.x >> 6;
    #pragma unroll
    for (int i = 0; i < 16; i++) {
        int fl = 4*i + r;
        tile[fl][lane] = s[(((t << 7) + fi0 + fl) << 6) + lane];
    }
    __syncthreads();
    #pragma unroll
    for (int i = 0; i < 16; i++) {
        int cc = 4*i + r;
        outp[cc*16384 + (t << 7) + fi0 + lane] = tile[lane][cc];
    }
}

// ---------------------------------------------------------------------------
// in_proj (rstd fused), both directions in one launch.
// grid = 2 * POS/16 blocks of 128 threads; thread j owns 4 output channels.
__global__ __launch_bounds__(128) void k_inproj(const float* __restrict__ seq_in,
                                                const float* __restrict__ nw_s,
                                                const float* __restrict__ ipw_s,
                                                float* __restrict__ xc_pre,
                                                float* __restrict__ zbuf) {
    __shared__ float xn[16][64];
    int dir = blockIdx.x >> 10;              // 1024 blocks per dir
    int g0  = (blockIdx.x & 1023) << 4;
    size_t dirOff = (size_t)dir * POS * DDIM;
    const float* nw  = nw_s  + dir*CDIM;
    const float* ipw = ipw_s + (size_t)dir * 2*DDIM*CDIM;

    int wv   = threadIdx.x >> 6;   // wave 0..1
    int lane = threadIdx.x & 63;
    float nwv = nw[lane];
    #pragma unroll
    for (int pi = wv; pi < 16; pi += 2) {
        int p = g0 + pi;
        int row = p >> 7, tau = p & 127;
        int s = dir ? (127 - tau) : tau;
        int q = (row << 7) + s;
        float v = seq_in[(q << 6) + lane];
        float ss = v*v;
        #pragma unroll
        for (int off = 32; off; off >>= 1) ss += __shfl_xor(ss, off, 64);
        float rs = rsqrtf(ss*(1.0f/64.0f) + 1e-5f);
        xn[pi][lane] = v*rs*nwv;
    }
    __syncthreads();

    int j = threadIdx.x;   // 0..127
    const float4* w0p = (const float4*)(ipw + (j << 6));
    const float4* w1p = (const float4*)(ipw + ((j + 128) << 6));
    const float4* w2p = (const float4*)(ipw + ((j + 256) << 6));
    const float4* w3p = (const float4*)(ipw + ((j + 384) << 6));
    float acc0[16], acc1[16], acc2[16], acc3[16];
    #pragma unroll
    for (int i = 0; i < 16; i++) { acc0[i] = 0.f; acc1[i] = 0.f; acc2[i] = 0.f; acc3[i] = 0.f; }
    #pragma unroll 4
    for (int k4 = 0; k4 < 16; k4++) {
        float4 wa = w0p[k4], wb = w1p[k4], wc = w2p[k4], wd = w3p[k4];
        #pragma unroll
        for (int i = 0; i < 16; i++) {
            float4 xv = *((const float4*)&xn[i][k4 << 2]);
            acc0[i] += dot4(wa, xv);
            acc1[i] += dot4(wb, xv);
            acc2[i] += dot4(wc, xv);
            acc3[i] += dot4(wd, xv);
        }
    }
    #pragma unroll
    for (int i = 0; i < 16; i++) {
        size_t base = dirOff + (size_t)(g0 + i)*DDIM;
        xc_pre[base + j]       = acc0[i];
        xc_pre[base + j + 128] = acc1[i];
        zbuf  [base + j]       = acc2[i];
        zbuf  [base + j + 128] = acc3[i];
    }
}

// ---------------------------------------------------------------------------
// causal dwconv(K=4)+silu fused with x_proj (256->36), dt_proj(4->256)+softplus.
// Writes xcb, dt, and dblg (B||C part used by scan). grid = 2*POS/16 x 256.
__global__ __launch_bounds__(256) void k_convxproj(const float* __restrict__ xc_pre,
                                                   const float* __restrict__ cw_s,
                                                   const float* __restrict__ cb_s,
                                                   const float* __restrict__ xpw_s,
                                                   const float* __restrict__ dtw_s,
                                                   const float* __restrict__ dtb_s,
                                                   float* __restrict__ xcb,
                                                   float* __restrict__ dtout,
                                                   float* __restrict__ dblg) {
    __shared__ float lx[16][260];    // conv+silu output, padded stride
    __shared__ float rq[16][4];      // x_proj r-part for dt
    int dir = blockIdx.x >> 10;      // POS/16 = 1024 blocks per dir
    int g0  = (blockIdx.x & 1023) << 4;
    int tau0 = g0 & 127;
    size_t dirOff = (size_t)dir * POS * DDIM;
    const float* cw  = cw_s  + dir*DDIM*KCONV;
    const float* cb  = cb_s  + dir*DDIM;
    const float* xpw = xpw_s + (size_t)dir*36*DDIM;
    const float* dtw = dtw_s + dir*DDIM*RDIM;
    const float* dtb = dtb_s + dir*DDIM;
    int t = threadIdx.x;

    // conv + silu for this thread's channel (ch = t) at 16 positions
    float r[19];
    #pragma unroll
    for (int j = 0; j < 19; j++) {
        r[j] = (tau0 == 0 && j < 3) ? 0.f
             : xc_pre[dirOff + (size_t)(g0 - 3 + j)*DDIM + t];
    }
    float c0 = cw[t*4], c1 = cw[t*4+1], c2 = cw[t*4+2], c3 = cw[t*4+3];
    float cbv = cb[t];
    #pragma unroll
    for (int i = 0; i < 16; i++) {
        float a = cbv + c0*r[i] + c1*r[i+1] + c2*r[i+2] + c3*r[i+3];
        float sv = fast_silu(a);
        lx[i][t] = sv;
        xcb[dirOff + (size_t)(g0 + i)*DDIM + t] = sv;
    }
    __syncthreads();

    // x_proj: 16 pos x 36 outputs = 576; oid -> pos = oid&15, j = oid>>4
    #pragma unroll
    for (int rep = 0; rep < 3; rep++) {
        int oid = rep*256 + t;
        if (oid < 576) {
            int pos = oid & 15;
            int j   = oid >> 4;
            const float4* xr = (const float4*)&lx[pos][0];
            const float4* wr = (const float4*)(xpw + (j << 8));
            float a0 = 0.f, a1 = 0.f, a2 = 0.f, a3 = 0.f;
            #pragma unroll 4
            for (int k4 = 0; k4 < 64; k4 += 4) {
                float4 xv0 = xr[k4],   wv0 = wr[k4];
                float4 xv1 = xr[k4+1], wv1 = wr[k4+1];
                float4 xv2 = xr[k4+2], wv2 = wr[k4+2];
                float4 xv3 = xr[k4+3], wv3 = wr[k4+3];
                a0 += dot4(wv0, xv0);
                a1 += dot4(wv1, xv1);
                a2 += dot4(wv2, xv2);
                a3 += dot4(wv3, xv3);
            }
            float v = (a0 + a1) + (a2 + a3);
            if (j < 4) rq[pos][j] = v;
            else dblg[(size_t)dir*POS*32 + (size_t)(g0 + pos)*32 + (j - 4)] = v;
        }
    }
    __syncthreads();

    // dt_proj + softplus for channel t at 16 positions
    float dbv = dtb[t];
    float4 tw = *((const float4*)(dtw + t*4));
    #pragma unroll
    for (int i = 0; i < 16; i++) {
        float a = dbv + rq[i][0]*tw.x + rq[i][1]*tw.y + rq[i][2]*tw.z + rq[i][3]*tw.w;
        float sp = (a > 0.f) ? (a + log1pf(__expf(-a))) : log1pf(__expf(a));
        dtout[dirOff + (size_t)(g0 + i)*DDIM + t] = sp;
    }
}

// ---------------------------------------------------------------------------
// selective scan. Block = (dir,row), 1024 threads: thread = (ch, quarter) with
// 4 n-states each; shfl_xor(1,2) combine. dt precomputed. Fuses +D*xc and
// *silu(z). Writes y in UNREVERSED (q-indexed) layout.
__global__ __launch_bounds__(1024) void k_scan(const float* __restrict__ xc,
                                               const float* __restrict__ dt,
                                               const float* __restrict__ dblg,  // [.][pos][32] B||C
                                               const float* __restrict__ Alog_s,
                                               const float* __restrict__ Dp_s,
                                               const float* __restrict__ zbuf,
                                               float* __restrict__ y) {
    __shared__ float sbc[128*32];   // B[16],C[16] per tau: 16 KiB
    int dir = blockIdx.x >> 7;      // 128 blocks per dir
    int row = blockIdx.x & 127;
    int ch  = threadIdx.x >> 2;
    int q   = threadIdx.x & 3;
    int s0  = q << 2;               // state offset 0,4,8,12
    size_t dirOff = (size_t)dir * POS * DDIM;
    const float* Alog = Alog_s + dir*DDIM*NSTATE;
    const float* Dp   = Dp_s   + dir*DDIM;

    {   // stage this row's B/C (linear float4 copy, 1024 float4s)
        const float4* src = (const float4*)(dblg + (size_t)dir*POS*32
                                            + (size_t)row*128*32);
        float4* dst = (float4*)sbc;
        for (int i = threadIdx.x; i < 128*32/4; i += 1024) dst[i] = src[i];
    }
    float4 av = *((const float4*)(Alog + ch*16 + s0));
    float a0 = -__expf(av.x), a1 = -__expf(av.y);
    float a2 = -__expf(av.z), a3 = -__expf(av.w);
    float h0 = 0.f, h1 = 0.f, h2 = 0.f, h3 = 0.f;
    float dv = Dp[ch];
    __syncthreads();

    size_t off = dirOff + ((size_t)row*128)*DDIM + ch;   // tau=0 of this row
    const size_t ybase = off;                             // y indexed by s
    // depth-2 software pipeline on the xc/z/dt streams
    float x0 = xc[off],        z0 = zbuf[off],        d0 = dt[off];
    float x1 = xc[off + DDIM], z1 = zbuf[off + DDIM], d1 = dt[off + DDIM];
    for (int tau = 0; tau < 128; tau++) {
        float x2 = 0.f, z2 = 0.f, d2 = 0.f;
        if (tau + 2 < 128) {
            size_t offn = off + 2*DDIM;
            x2 = xc[offn]; z2 = zbuf[offn]; d2 = dt[offn];
        }
        float dtv = d0;
        float dtx = dtv*x0;
        float4 B = *((const float4*)&sbc[tau*32 + s0]);
        float4 C = *((const float4*)&sbc[tau*32 + 16 + s0]);
        float dA0 = __expf(dtv*a0);
        float dA1 = __expf(dtv*a1);
        float dA2 = __expf(dtv*a2);
        float dA3 = __expf(dtv*a3);
        h0 = h0*dA0 + dtx*B.x;
        h1 = h1*dA1 + dtx*B.y;
        h2 = h2*dA2 + dtx*B.z;
        h3 = h3*dA3 + dtx*B.w;
        float acc = (h0*C.x + h1*C.y) + (h2*C.z + h3*C.w);
        acc += __shfl_xor(acc, 1, 64);
        acc += __shfl_xor(acc, 2, 64);
        if (q == 0) {
            float yv = (acc + dv*x0) * fast_silu(z0);
            int s = dir ? (127 - tau) : tau;
            y[ybase + (size_t)s*DDIM] = yv;  // q-layout
        }
        x0 = x1; z0 = z1; d0 = d1; x1 = x2; z1 = z2; d1 = d2; off += DDIM;
    }
}

// ---------------------------------------------------------------------------
// out_proj (256->64) both dirs + bidir residual concat + stage linear
// (128->64) + residual. grid = POS/32 blocks (512) of 256 threads.
__global__ __launch_bounds__(256) void k_outlin(const float* __restrict__ y,  // [2][POS][256], q-layout
                                                const float* __restrict__ opw_s,
                                                const float* __restrict__ seq_in,
                                                const float* __restrict__ lw,
                                                const float* __restrict__ lb,
                                                float* __restrict__ seq_out,
                                                int twrite) {
    __shared__ float cat[32][128];   // 16 KiB
    int tid = threadIdx.x;
    int g0  = blockIdx.x << 5;       // 32 positions per block

    // ---- phase 1: out_proj ----
    {
        int cc  = tid & 63;
        int q   = tid >> 6;          // 0..3
        int dir = q & 1;
        int pg  = q >> 1;            // position half: 0 or 1
        int p0  = g0 + (pg << 4);
        const float* yb = y + (size_t)dir*POS*DDIM + (size_t)p0*DDIM;
        const float4* wp = (const float4*)(opw_s + (size_t)dir*CDIM*DDIM
                                           + (size_t)cc*DDIM);
        float acc[16];
        #pragma unroll
        for (int i = 0; i < 16; i++) acc[i] = 0.f;
        for (int k4 = 0; k4 < 64; k4++) {
            float4 w = wp[k4];
            #pragma unroll
            for (int i = 0; i < 16; i++) {
                float4 xv = *((const float4*)(yb + (size_t)i*DDIM + (k4 << 2)));
                acc[i] += dot4(w, xv);
            }
        }
        #pragma unroll
        for (int i = 0; i < 16; i++) {
            float siv = seq_in[(size_t)(p0 + i)*CDIM + cc];
            cat[(pg << 4) + i][(dir << 6) + cc] = siv + acc[i];
        }
    }
    __syncthreads();

    // ---- phase 2: stage linear (128 -> 64) + residual ----
    {
        int cc  = tid & 63;
        int grp = tid >> 6;          // 0..3
        int ib  = grp << 3;          // 8 positions per thread
        float bv = lb[cc];
        float acc2[8];
        #pragma unroll
        for (int ii = 0; ii < 8; ii++) acc2[ii] = bv;
        for (int k4 = 0; k4 < 32; k4++) {
            int k = k4 << 2;
            float w0 = lw[(k + 0)*64 + cc];
            float w1 = lw[(k + 1)*64 + cc];
            float w2 = lw[(k + 2)*64 + cc];
            float w3 = lw[(k + 3)*64 + cc];
            #pragma unroll
            for (int ii = 0; ii < 8; ii++) {
                float4 cv = *((const float4*)&cat[ib + ii][k]);
                acc2[ii] += cv.x*w0 + cv.y*w1 + cv.z*w2 + cv.w*w3;
            }
        }
        #pragma unroll
        for (int ii = 0; ii < 8; ii++) {
            int p = g0 + ib + ii;
            float val = acc2[ii] + seq_in[(size_t)p*CDIM + cc];
            if (twrite) {
                // stage-1 -> stage-2 layout: dst position (t*128+fi), p = fi*128+t
                int dstp = ((p & 127) << 7) + (p >> 7);
                seq_out[((size_t)dstp << 6) + cc] = val;
            } else {
                seq_out[((size_t)p << 6) + cc] = val;
            }
        }
    }
}

// ---------------------------------------------------------------------------
extern "C" void kernel_launch(void* const* d_in, const int* in_sizes, int n_in,
                              void* d_out, int out_size, void* d_ws, size_t ws_size,
                              hipStream_t stream) {
    (void)in_sizes; (void)n_in; (void)out_size; (void)ws_size;
    const float* x      = (const float*)d_in[0];
    const float* norm_w = (const float*)d_in[1];
    const float* ipw    = (const float*)d_in[2];
    const float* cw     = (const float*)d_in[3];
    const float* cb     = (const float*)d_in[4];
    const float* xpw    = (const float*)d_in[5];
    const float* dtw    = (const float*)d_in[6];
    const float* dtbp   = (const float*)d_in[7];
    const float* Alog   = (const float*)d_in[8];
    const float* Dp     = (const float*)d_in[9];
    const float* opw    = (const float*)d_in[10];
    const float* tlw    = (const float*)d_in[11];
    const float* tlb    = (const float*)d_in[12];
    const float* flw    = (const float*)d_in[13];
    const float* flb    = (const float*)d_in[14];
    float* outp = (float*)d_out;

    float* ws       = (float*)d_ws;
    float* seq_in   = ws;                            // POS*64
    float* xc_pre   = seq_in  + (size_t)POS*64;      // 2*POS*256 (reused as y)
    float* zbuf     = xc_pre  + (size_t)2*POS*256;   // 2*POS*256
    float* xcb      = zbuf    + (size_t)2*POS*256;   // 2*POS*256
    float* dtbuf    = xcb     + (size_t)2*POS*256;   // 2*POS*256
    float* dblbuf   = dtbuf   + (size_t)2*POS*256;   // 2*POS*32
    float* seq_out  = dblbuf  + (size_t)2*POS*32;    // POS*64

    auto stage = [&](int st, const float* lw, const float* lb, int twrite,
                     float* sout) {
        int pi = 2*st;
        k_inproj   <<<2*POS/16, 128, 0, stream>>>(seq_in,
                        norm_w + pi*CDIM, ipw + (size_t)pi*2*DDIM*CDIM,
                        xc_pre, zbuf);
        k_convxproj<<<2*POS/16, 256, 0, stream>>>(xc_pre,
                        cw + pi*DDIM*KCONV, cb + pi*DDIM,
                        xpw + (size_t)pi*36*DDIM,
                        dtw + pi*DDIM*RDIM, dtbp + pi*DDIM,
                        xcb, dtbuf, dblbuf);
        k_scan     <<<2*NROW, 1024, 0, stream>>>(xcb, dtbuf, dblbuf,
                        Alog + (size_t)pi*DDIM*NSTATE, Dp + pi*DDIM,
                        zbuf, xc_pre);   // y written into xc_pre (q-layout)
        k_outlin   <<<POS/32, 256, 0, stream>>>(xc_pre,
                        opw + (size_t)pi*CDIM*DDIM, seq_in, lw, lb,
                        sout, twrite);
    };

    // stage 1 (time mamba), output written directly in stage-2 layout
    k_prep1<<<256, 256, 0, stream>>>(x, seq_in);
    stage(0, tlw, tlb, 1, seq_out);

    // stage 2 (freq mamba)
    {
        float* tmp = seq_in; seq_in = seq_out; seq_out = tmp;
    }
    stage(1, flw, flb, 0, seq_out);

    // write back
    k_final<<<256, 256, 0, stream>>>(seq_out, outp);
}

// Round 13
// 583.179 us; speedup vs baseline: 1.3440x; 1.0873x over previous
//
#include <hip/hip_runtime.h>
#include <math.h>

// Problem constants (b=1, c=64, t=128, f=128, expand=4, n=16, K=4, r=4)
#define LSEQ 128          // sequence length (both stages)
#define NROW 128          // rows per stage
#define POS (LSEQ*NROW)   // 16384 positions
#define CDIM 64
#define DDIM 256
#define NSTATE 16
#define RDIM 4
#define KCONV 4

static __forceinline__ __device__ float dot4(float4 a, float4 b) {
    return a.x*b.x + a.y*b.y + a.z*b.z + a.w*b.w;
}
static __forceinline__ __device__ float fast_silu(float v) {
    return v * __builtin_amdgcn_rcpf(1.f + __expf(-v));
}

// ---------------------------------------------------------------------------
// Stage-1 input prep: seq_in[(fi*128 + t)*64 + cc] = x[(cc*128 + t)*128 + fi]
__global__ __launch_bounds__(256) void k_prep1(const float* __restrict__ x,
                                               float* __restrict__ seq_in) {
    __shared__ float tile[64][65];
    int t   = blockIdx.x & 127;
    int fi0 = (blockIdx.x >> 7) << 6;  // 0 or 64
    int lane = threadIdx.x & 63;
    int r    = threadIdx.x >> 6;       // 0..3
    #pragma unroll
    for (int i = 0; i < 16; i++) {
        int cc = 4*i + r;
        tile[cc][lane] = x[cc*16384 + t*128 + fi0 + lane];
    }
    __syncthreads();
    #pragma unroll
    for (int i = 0; i < 16; i++) {
        int fl = 4*i + r;
        seq_in[(fi0 + fl)*8192 + t*64 + lane] = tile[lane][fl];
    }
}

// Final: out[cc*16384 + t*128 + fi] = s[(t*128+fi)*64 + cc]
__global__ __launch_bounds__(256) void k_final(const float* __restrict__ s,
                                               float* __restrict__ outp) {
    __shared__ float tile[64][65];
    int t   = blockIdx.x & 127;
    int fi0 = (blockIdx.x >> 7) << 6;
    int lane = threadIdx.x & 63;
    int r    = threadIdx.x >> 6;
    #pragma unroll
    for (int i = 0; i < 16; i++) {
        int fl = 4*i + r;
        tile[fl][lane] = s[(((t << 7) + fi0 + fl) << 6) + lane];
    }
    __syncthreads();
    #pragma unroll
    for (int i = 0; i < 16; i++) {
        int cc = 4*i + r;
        outp[cc*16384 + (t << 7) + fi0 + lane] = tile[lane][cc];
    }
}

// ---------------------------------------------------------------------------
// in_proj (rstd fused), both directions in one launch.
// grid = 2 * POS/16 blocks of 128 threads; thread j owns 4 output channels.
__global__ __launch_bounds__(128) void k_inproj(const float* __restrict__ seq_in,
                                                const float* __restrict__ nw_s,
                                                const float* __restrict__ ipw_s,
                                                float* __restrict__ xc_pre,
                                                float* __restrict__ zbuf) {
    __shared__ float xn[16][64];
    int dir = blockIdx.x >> 10;              // 1024 blocks per dir
    int g0  = (blockIdx.x & 1023) << 4;
    size_t dirOff = (size_t)dir * POS * DDIM;
    const float* nw  = nw_s  + dir*CDIM;
    const float* ipw = ipw_s + (size_t)dir * 2*DDIM*CDIM;

    int wv   = threadIdx.x >> 6;   // wave 0..1
    int lane = threadIdx.x & 63;
    float nwv = nw[lane];
    #pragma unroll
    for (int pi = wv; pi < 16; pi += 2) {
        int p = g0 + pi;
        int row = p >> 7, tau = p & 127;
        int s = dir ? (127 - tau) : tau;
        int q = (row << 7) + s;
        float v = seq_in[(q << 6) + lane];
        float ss = v*v;
        #pragma unroll
        for (int off = 32; off; off >>= 1) ss += __shfl_xor(ss, off, 64);
        float rs = rsqrtf(ss*(1.0f/64.0f) + 1e-5f);
        xn[pi][lane] = v*rs*nwv;
    }
    __syncthreads();

    int j = threadIdx.x;   // 0..127
    const float4* w0p = (const float4*)(ipw + (j << 6));
    const float4* w1p = (const float4*)(ipw + ((j + 128) << 6));
    const float4* w2p = (const float4*)(ipw + ((j + 256) << 6));
    const float4* w3p = (const float4*)(ipw + ((j + 384) << 6));
    float acc0[16], acc1[16], acc2[16], acc3[16];
    #pragma unroll
    for (int i = 0; i < 16; i++) { acc0[i] = 0.f; acc1[i] = 0.f; acc2[i] = 0.f; acc3[i] = 0.f; }
    #pragma unroll 4
    for (int k4 = 0; k4 < 16; k4++) {
        float4 wa = w0p[k4], wb = w1p[k4], wc = w2p[k4], wd = w3p[k4];
        #pragma unroll
        for (int i = 0; i < 16; i++) {
            float4 xv = *((const float4*)&xn[i][k4 << 2]);
            acc0[i] += dot4(wa, xv);
            acc1[i] += dot4(wb, xv);
            acc2[i] += dot4(wc, xv);
            acc3[i] += dot4(wd, xv);
        }
    }
    #pragma unroll
    for (int i = 0; i < 16; i++) {
        size_t base = dirOff + (size_t)(g0 + i)*DDIM;
        xc_pre[base + j]       = acc0[i];
        xc_pre[base + j + 128] = acc1[i];
        zbuf  [base + j]       = acc2[i];
        zbuf  [base + j + 128] = acc3[i];
    }
}

// ---------------------------------------------------------------------------
// causal dwconv(K=4)+silu fused with x_proj (256->36), dt_proj(4->256)+softplus.
// Writes xcb, dt, and dblg (B||C part used by scan). grid = 2*POS/16 x 256.
__global__ __launch_bounds__(256) void k_convxproj(const float* __restrict__ xc_pre,
                                                   const float* __restrict__ cw_s,
                                                   const float* __restrict__ cb_s,
                                                   const float* __restrict__ xpw_s,
                                                   const float* __restrict__ dtw_s,
                                                   const float* __restrict__ dtb_s,
                                                   float* __restrict__ xcb,
                                                   float* __restrict__ dtout,
                                                   float* __restrict__ dblg) {
    __shared__ float lx[16][260];    // conv+silu output, padded stride
    __shared__ float rq[16][4];      // x_proj r-part for dt
    int dir = blockIdx.x >> 10;      // POS/16 = 1024 blocks per dir
    int g0  = (blockIdx.x & 1023) << 4;
    int tau0 = g0 & 127;
    size_t dirOff = (size_t)dir * POS * DDIM;
    const float* cw  = cw_s  + dir*DDIM*KCONV;
    const float* cb  = cb_s  + dir*DDIM;
    const float* xpw = xpw_s + (size_t)dir*36*DDIM;
    const float* dtw = dtw_s + dir*DDIM*RDIM;
    const float* dtb = dtb_s + dir*DDIM;
    int t = threadIdx.x;

    // conv + silu for this thread's channel (ch = t) at 16 positions
    float r[19];
    #pragma unroll
    for (int j = 0; j < 19; j++) {
        r[j] = (tau0 == 0 && j < 3) ? 0.f
             : xc_pre[dirOff + (size_t)(g0 - 3 + j)*DDIM + t];
    }
    float c0 = cw[t*4], c1 = cw[t*4+1], c2 = cw[t*4+2], c3 = cw[t*4+3];
    float cbv = cb[t];
    #pragma unroll
    for (int i = 0; i < 16; i++) {
        float a = cbv + c0*r[i] + c1*r[i+1] + c2*r[i+2] + c3*r[i+3];
        float sv = fast_silu(a);
        lx[i][t] = sv;
        xcb[dirOff + (size_t)(g0 + i)*DDIM + t] = sv;
    }
    __syncthreads();

    // x_proj: 16 pos x 36 outputs = 576; oid -> pos = oid&15, j = oid>>4
    #pragma unroll
    for (int rep = 0; rep < 3; rep++) {
        int oid = rep*256 + t;
        if (oid < 576) {
            int pos = oid & 15;
            int j   = oid >> 4;
            const float4* xr = (const float4*)&lx[pos][0];
            const float4* wr = (const float4*)(xpw + (j << 8));
            float a0 = 0.f, a1 = 0.f, a2 = 0.f, a3 = 0.f;
            #pragma unroll 4
            for (int k4 = 0; k4 < 64; k4 += 4) {
                float4 xv0 = xr[k4],   wv0 = wr[k4];
                float4 xv1 = xr[k4+1], wv1 = wr[k4+1];
                float4 xv2 = xr[k4+2], wv2 = wr[k4+2];
                float4 xv3 = xr[k4+3], wv3 = wr[k4+3];
                a0 += dot4(wv0, xv0);
                a1 += dot4(wv1, xv1);
                a2 += dot4(wv2, xv2);
                a3 += dot4(wv3, xv3);
            }
            float v = (a0 + a1) + (a2 + a3);
            if (j < 4) rq[pos][j] = v;
            else dblg[(size_t)dir*POS*32 + (size_t)(g0 + pos)*32 + (j - 4)] = v;
        }
    }
    __syncthreads();

    // dt_proj + softplus for channel t at 16 positions
    float dbv = dtb[t];
    float4 tw = *((const float4*)(dtw + t*4));
    #pragma unroll
    for (int i = 0; i < 16; i++) {
        float a = dbv + rq[i][0]*tw.x + rq[i][1]*tw.y + rq[i][2]*tw.z + rq[i][3]*tw.w;
        float sp = (a > 0.f) ? (a + log1pf(__expf(-a))) : log1pf(__expf(a));
        dtout[dirOff + (size_t)(g0 + i)*DDIM + t] = sp;
    }
}

// ---------------------------------------------------------------------------
// selective scan. Block = (dir,row), 1024 threads: thread = (ch, quarter) with
// 4 n-states each; shfl_xor(1,2) combine. dt precomputed. Fuses +D*xc and
// *silu(z). Writes y in UNREVERSED (q-indexed) layout.
__global__ __launch_bounds__(1024) void k_scan(const float* __restrict__ xc,
                                               const float* __restrict__ dt,
                                               const float* __restrict__ dblg,  // [.][pos][32] B||C
                                               const float* __restrict__ Alog_s,
                                               const float* __restrict__ Dp_s,
                                               const float* __restrict__ zbuf,
                                               float* __restrict__ y) {
    __shared__ float sbc[128*32];   // B[16],C[16] per tau: 16 KiB
    int dir = blockIdx.x >> 7;      // 128 blocks per dir
    int row = blockIdx.x & 127;
    int ch  = threadIdx.x >> 2;
    int q   = threadIdx.x & 3;
    int s0  = q << 2;               // state offset 0,4,8,12
    size_t dirOff = (size_t)dir * POS * DDIM;
    const float* Alog = Alog_s + dir*DDIM*NSTATE;
    const float* Dp   = Dp_s   + dir*DDIM;

    {   // stage this row's B/C (linear float4 copy, 1024 float4s)
        const float4* src = (const float4*)(dblg + (size_t)dir*POS*32
                                            + (size_t)row*128*32);
        float4* dst = (float4*)sbc;
        for (int i = threadIdx.x; i < 128*32/4; i += 1024) dst[i] = src[i];
    }
    float4 av = *((const float4*)(Alog + ch*16 + s0));
    float a0 = -__expf(av.x), a1 = -__expf(av.y);
    float a2 = -__expf(av.z), a3 = -__expf(av.w);
    float h0 = 0.f, h1 = 0.f, h2 = 0.f, h3 = 0.f;
    float dv = Dp[ch];
    __syncthreads();

    size_t off = dirOff + ((size_t)row*128)*DDIM + ch;   // tau=0 of this row
    const size_t ybase = off;                             // y indexed by s
    // depth-2 software pipeline on the xc/z/dt streams
    float x0 = xc[off],        z0 = zbuf[off],        d0 = dt[off];
    float x1 = xc[off + DDIM], z1 = zbuf[off + DDIM], d1 = dt[off + DDIM];
    for (int tau = 0; tau < 128; tau++) {
        float x2 = 0.f, z2 = 0.f, d2 = 0.f;
        if (tau + 2 < 128) {
            size_t offn = off + 2*DDIM;
            x2 = xc[offn]; z2 = zbuf[offn]; d2 = dt[offn];
        }
        float dtv = d0;
        float dtx = dtv*x0;
        float4 B = *((const float4*)&sbc[tau*32 + s0]);
        float4 C = *((const float4*)&sbc[tau*32 + 16 + s0]);
        float dA0 = __expf(dtv*a0);
        float dA1 = __expf(dtv*a1);
        float dA2 = __expf(dtv*a2);
        float dA3 = __expf(dtv*a3);
        h0 = h0*dA0 + dtx*B.x;
        h1 = h1*dA1 + dtx*B.y;
        h2 = h2*dA2 + dtx*B.z;
        h3 = h3*dA3 + dtx*B.w;
        float acc = (h0*C.x + h1*C.y) + (h2*C.z + h3*C.w);
        acc += __shfl_xor(acc, 1, 64);
        acc += __shfl_xor(acc, 2, 64);
        if (q == 0) {
            float yv = (acc + dv*x0) * fast_silu(z0);
            int s = dir ? (127 - tau) : tau;
            y[ybase + (size_t)s*DDIM] = yv;  // q-layout
        }
        x0 = x1; z0 = z1; d0 = d1; x1 = x2; z1 = z2; d1 = d2; off += DDIM;
    }
}

// ---------------------------------------------------------------------------
// out_proj (256->64) both dirs + bidir residual concat + stage linear
// (128->64) + residual. grid = POS/16 blocks (1024) of 256 threads.
// Phase 0: stage y (both dirs) into LDS, coalesced.
// Phase 1: wave = (dir, pos-half); lane = cc. y reads are LDS same-address
//   broadcasts (conflict-free); each thread streams ONE weight row (1 KB).
// Phase 2: stage linear; cat broadcast reads, lw coalesced.
__global__ __launch_bounds__(256) void k_outlin(const float* __restrict__ y,  // [2][POS][256], q-layout
                                                const float* __restrict__ opw_s,
                                                const float* __restrict__ seq_in,
                                                const float* __restrict__ lw,
                                                const float* __restrict__ lb,
                                                float* __restrict__ seq_out,
                                                int twrite) {
    __shared__ float ly[2*16*256];   // 32 KiB
    __shared__ float cat[16][128];   // 8 KiB
    int tid = threadIdx.x;
    int g0  = blockIdx.x << 4;       // 16 positions per block

    // ---- phase 0: stage y (both dirs), fully coalesced ----
    {
        const float4* src0 = (const float4*)(y + (size_t)g0*DDIM);
        const float4* src1 = (const float4*)(y + (size_t)POS*DDIM + (size_t)g0*DDIM);
        float4* dst = (float4*)ly;
        #pragma unroll
        for (int i = 0; i < 4; i++) dst[tid + i*256]        = src0[tid + i*256];
        #pragma unroll
        for (int i = 0; i < 4; i++) dst[1024 + tid + i*256] = src1[tid + i*256];
    }
    __syncthreads();

    // ---- phase 1: out_proj ----
    {
        int cc  = tid & 63;
        int q   = tid >> 6;          // wave id: 0..3
        int dir = q & 1;
        int ph  = q >> 1;            // position half: 0 or 1
        const float4* wp = (const float4*)(opw_s + (size_t)dir*CDIM*DDIM
                                           + (size_t)cc*DDIM);
        const float4* yl = ((const float4*)ly) + dir*1024 + ph*512;
        float acc[8];
        #pragma unroll
        for (int p = 0; p < 8; p++) acc[p] = 0.f;
        for (int k4 = 0; k4 < 64; k4++) {
            float4 w = wp[k4];
            #pragma unroll
            for (int p = 0; p < 8; p++) {
                float4 xv = yl[p*64 + k4];   // same addr across wave: broadcast
                acc[p] += dot4(w, xv);
            }
        }
        #pragma unroll
        for (int p = 0; p < 8; p++) {
            int pos = (ph << 3) + p;
            float siv = seq_in[(size_t)(g0 + pos)*CDIM + cc];
            cat[pos][(dir << 6) + cc] = siv + acc[p];
        }
    }
    __syncthreads();

    // ---- phase 2: stage linear (128 -> 64) + residual ----
    {
        int cc  = tid & 63;
        int grp = tid >> 6;          // 0..3
        int ib  = grp << 2;          // 4 positions per thread
        float bv = lb[cc];
        float acc2[4] = {bv, bv, bv, bv};
        for (int k4 = 0; k4 < 32; k4++) {
            int k = k4 << 2;
            float w0 = lw[(k + 0)*64 + cc];
            float w1 = lw[(k + 1)*64 + cc];
            float w2 = lw[(k + 2)*64 + cc];
            float w3 = lw[(k + 3)*64 + cc];
            #pragma unroll
            for (int ii = 0; ii < 4; ii++) {
                float4 cv = *((const float4*)&cat[ib + ii][k]);
                acc2[ii] += cv.x*w0 + cv.y*w1 + cv.z*w2 + cv.w*w3;
            }
        }
        #pragma unroll
        for (int ii = 0; ii < 4; ii++) {
            int p = g0 + ib + ii;
            float val = acc2[ii] + seq_in[(size_t)p*CDIM + cc];
            if (twrite) {
                // stage-1 -> stage-2 layout: dst position (t*128+fi), p = fi*128+t
                int dstp = ((p & 127) << 7) + (p >> 7);
                seq_out[((size_t)dstp << 6) + cc] = val;
            } else {
                seq_out[((size_t)p << 6) + cc] = val;
            }
        }
    }
}

// ---------------------------------------------------------------------------
extern "C" void kernel_launch(void* const* d_in, const int* in_sizes, int n_in,
                              void* d_out, int out_size, void* d_ws, size_t ws_size,
                              hipStream_t stream) {
    (void)in_sizes; (void)n_in; (void)out_size; (void)ws_size;
    const float* x      = (const float*)d_in[0];
    const float* norm_w = (const float*)d_in[1];
    const float* ipw    = (const float*)d_in[2];
    const float* cw     = (const float*)d_in[3];
    const float* cb     = (const float*)d_in[4];
    const float* xpw    = (const float*)d_in[5];
    const float* dtw    = (const float*)d_in[6];
    const float* dtbp   = (const float*)d_in[7];
    const float* Alog   = (const float*)d_in[8];
    const float* Dp     = (const float*)d_in[9];
    const float* opw    = (const float*)d_in[10];
    const float* tlw    = (const float*)d_in[11];
    const float* tlb    = (const float*)d_in[12];
    const float* flw    = (const float*)d_in[13];
    const float* flb    = (const float*)d_in[14];
    float* outp = (float*)d_out;

    float* ws       = (float*)d_ws;
    float* seq_in   = ws;                            // POS*64
    float* xc_pre   = seq_in  + (size_t)POS*64;      // 2*POS*256 (reused as y)
    float* zbuf     = xc_pre  + (size_t)2*POS*256;   // 2*POS*256
    float* xcb      = zbuf    + (size_t)2*POS*256;   // 2*POS*256
    float* dtbuf    = xcb     + (size_t)2*POS*256;   // 2*POS*256
    float* dblbuf   = dtbuf   + (size_t)2*POS*256;   // 2*POS*32
    float* seq_out  = dblbuf  + (size_t)2*POS*32;    // POS*64

    auto stage = [&](int st, const float* lw, const float* lb, int twrite,
                     float* sout) {
        int pi = 2*st;
        k_inproj   <<<2*POS/16, 128, 0, stream>>>(seq_in,
                        norm_w + pi*CDIM, ipw + (size_t)pi*2*DDIM*CDIM,
                        xc_pre, zbuf);
        k_convxproj<<<2*POS/16, 256, 0, stream>>>(xc_pre,
                        cw + pi*DDIM*KCONV, cb + pi*DDIM,
                        xpw + (size_t)pi*36*DDIM,
                        dtw + pi*DDIM*RDIM, dtbp + pi*DDIM,
                        xcb, dtbuf, dblbuf);
        k_scan     <<<2*NROW, 1024, 0, stream>>>(xcb, dtbuf, dblbuf,
                        Alog + (size_t)pi*DDIM*NSTATE, Dp + pi*DDIM,
                        zbuf, xc_pre);   // y written into xc_pre (q-layout)
        k_outlin   <<<POS/16, 256, 0, stream>>>(xc_pre,
                        opw + (size_t)pi*CDIM*DDIM, seq_in, lw, lb,
                        sout, twrite);
    };

    // stage 1 (time mamba), output written directly in stage-2 layout
    k_prep1<<<256, 256, 0, stream>>>(x, seq_in);
    stage(0, tlw, tlb, 1, seq_out);

    // stage 2 (freq mamba)
    {
        float* tmp = seq_in; seq_in = seq_out; seq_out = tmp;
    }
    stage(1, flw, flb, 0, seq_out);

    // write back
    k_final<<<256, 256, 0, stream>>>(seq_out, outp);
}